// Round 15
// baseline (35.897 us; speedup 1.0000x reference)
//
#include <hip/hip_runtime.h>
#include <math.h>

// x: (8, 12, 4096, 64) f32. Group = (b, t): 768 elements x[b, h, t, c].
// out = delta * 2^-rint(-log2(max(x/delta,1e-8))), delta = group max.
//
// Round-15: same pair-per-wave mapping as round 14, but the 24 loaded values
// are PINNED in VGPRs via empty asm (compiler kept allocating 24 VGPRs and
// rematerializing the loads -> second L2 read pass). Now: load once, reduce,
// compute, store -- true single pass.
//
// Fast path PURE INTEGER (bit-identical since round 5): k = rint(-log2(rf))
// = (0x3FB504F3 - bits(rf)) >> 23 (cliff at sqrt(2)'s mantissa). Elements
// within 2048 mantissa-ulps of a cliff (~0.05%) recompute via the exact ref
// chain (IEEE f32 div, correctly-rounded log, /fl32(ln2), round-half-even).

#define BB 8
#define HH 12
#define TT 4096
#define CC 64
#define HSTRIDE ((size_t)TT * CC)   // stride between h planes, in floats

typedef float vf4 __attribute__((ext_vector_type(4)));

__global__ __launch_bounds__(256) void log2q_kernel(const float* __restrict__ x,
                                                    float* __restrict__ out) {
    const int wave = threadIdx.x >> 6;
    const int lane = threadIdx.x & 63;
    const int pair = (blockIdx.x << 2) | wave;   // 0..16383; 2 t-groups each
    const int b    = pair >> 11;                 // 2048 pairs per b
    const int t0   = (pair & 2047) << 1;         // first t of the pair

    // lane l -> h-plane offset (l>>5) within each plane-pair, float offset (l&31)*4
    const size_t base = (size_t)b * (HH * HSTRIDE)
                      + (size_t)t0 * CC
                      + (size_t)(lane >> 5) * HSTRIDE
                      + (size_t)((lane & 31) << 2);

    // ---- 6 fully-contiguous 1KB loads, unpacked to 24 scalars ----
    float r[24];
#pragma unroll
    for (int i = 0; i < 6; ++i) {
        const vf4 t = *reinterpret_cast<const vf4*>(x + base + (size_t)(2 * i) * HSTRIDE);
        r[4 * i + 0] = t.x; r[4 * i + 1] = t.y; r[4 * i + 2] = t.z; r[4 * i + 3] = t.w;
    }
    // pin: values become opaque -- compiler CANNOT rematerialize the loads
#pragma unroll
    for (int i = 0; i < 24; ++i) asm volatile("" : "+v"(r[i]));

    // ---- exact group max within the 32-lane t-row set: lane tree + 5 shfl ----
    float m = r[0];
#pragma unroll
    for (int i = 1; i < 24; ++i) m = fmaxf(m, r[i]);
    m = fmaxf(m, __shfl_xor(m, 1));
    m = fmaxf(m, __shfl_xor(m, 2));
    m = fmaxf(m, __shfl_xor(m, 4));
    m = fmaxf(m, __shfl_xor(m, 8));
    m = fmaxf(m, __shfl_xor(m, 32));
    const float delta = m;                               // max over this lane's (b,t) group
    const float rdelta = __builtin_amdgcn_rcpf(delta);   // fast-path reciprocal
    const int   dbits  = __float_as_int(delta);

#pragma unroll
    for (int i = 0; i < 6; ++i) {
        float o[4];
#pragma unroll
        for (int j = 0; j < 4; ++j) {
            const float rv = r[4 * i + j];
            const float rf = fmaxf(rv * rdelta, 1e-8f);
            const unsigned int bits = __float_as_uint(rf);
            const unsigned int diff = 0x3FB504F3u - bits;   // >0 for rf in [1e-8, ~1.4)
            int kq = (int)(diff >> 23);                     // exact rint(-log2(rf))
            const unsigned int d2 = (diff + 2048u) & 0x7FFFFFu;
            if (d2 < 4096u) {
                // near a half-integer cliff: replicate ref chain exactly
                const float ratio = fmaxf(rv / delta, 1e-8f);    // IEEE f32 div
                const float tt = (float)log((double)ratio);
                const float v2 = tt / 0x1.62e43p-1f;             // fl32(ln 2)
                kq = (int)rintf(-v2);
            }
            // out = delta * 2^-kq exactly, via exponent decrement (kq in [0,27])
            o[j] = __int_as_float(dbits - (kq << 23));
        }
        vf4 ov = {o[0], o[1], o[2], o[3]};
        *reinterpret_cast<vf4*>(out + base + (size_t)(2 * i) * HSTRIDE) = ov;
    }
}

extern "C" void kernel_launch(void* const* d_in, const int* in_sizes, int n_in,
                              void* d_out, int out_size, void* d_ws, size_t ws_size,
                              hipStream_t stream) {
    const float* x = (const float*)d_in[0];
    float* out = (float*)d_out;
    dim3 grid((BB * TT) / 8);   // 4096 blocks, 4 wave-pairs each (8 groups)
    dim3 block(256);
    log2q_kernel<<<grid, block, 0, stream>>>(x, out);
}

// Round 16
// 35.770 us; speedup vs baseline: 1.0035x; 1.0035x over previous
//
#include <hip/hip_runtime.h>
#include <math.h>

// x: (8, 12, 4096, 64) f32. Group = (b, t): 768 elements x[b, h, t, c].
// out = delta * 2^-rint(-log2(max(x/delta,1e-8))), delta = group max.
//
// Round-16: round-14 pair-per-wave structure, but stores are NONTEMPORAL
// while loads stay cacheable. Rationale: out is write-once/never-read; its
// L3 allocation evicts x between graph replays (round-13 FETCH=48MB shows
// only half of x survives). NT stores let x (100.7 MB) own the 256 MB
// Infinity Cache -> steady-state reads come from L3, HBM carries writes only.
//
// Fast path PURE INTEGER (bit-identical since round 5): k = rint(-log2(rf))
// = (0x3FB504F3 - bits(rf)) >> 23 (cliff at sqrt(2)'s mantissa). Elements
// within 2048 mantissa-ulps of a cliff (~0.05%) recompute via the exact ref
// chain (IEEE f32 div, correctly-rounded log, /fl32(ln2), round-half-even).

#define BB 8
#define HH 12
#define TT 4096
#define CC 64
#define HSTRIDE ((size_t)TT * CC)   // stride between h planes, in floats

typedef float vf4 __attribute__((ext_vector_type(4)));

__global__ __launch_bounds__(256) void log2q_kernel(const float* __restrict__ x,
                                                    float* __restrict__ out) {
    const int wave = threadIdx.x >> 6;
    const int lane = threadIdx.x & 63;
    const int pair = (blockIdx.x << 2) | wave;   // 0..16383; 2 t-groups each
    const int b    = pair >> 11;                 // 2048 pairs per b
    const int t0   = (pair & 2047) << 1;         // first t of the pair

    // lane l -> h-plane offset (l>>5) within each plane-pair, float offset (l&31)*4
    const size_t base = (size_t)b * (HH * HSTRIDE)
                      + (size_t)t0 * CC
                      + (size_t)(lane >> 5) * HSTRIDE
                      + (size_t)((lane & 31) << 2);

    // ---- 6 fully-contiguous 1KB cacheable loads ----
    vf4 v[6];
#pragma unroll
    for (int i = 0; i < 6; ++i)
        v[i] = *reinterpret_cast<const vf4*>(x + base + (size_t)(2 * i) * HSTRIDE);

    // ---- exact group max within the 32-lane t-row set: lane tree + 5 shfl ----
    float m = fmaxf(fmaxf(v[0].x, v[0].y), fmaxf(v[0].z, v[0].w));
#pragma unroll
    for (int i = 1; i < 6; ++i)
        m = fmaxf(m, fmaxf(fmaxf(v[i].x, v[i].y), fmaxf(v[i].z, v[i].w)));
    m = fmaxf(m, __shfl_xor(m, 1));
    m = fmaxf(m, __shfl_xor(m, 2));
    m = fmaxf(m, __shfl_xor(m, 4));
    m = fmaxf(m, __shfl_xor(m, 8));
    m = fmaxf(m, __shfl_xor(m, 32));
    const float delta = m;                               // max over this lane's (b,t) group
    const float rdelta = __builtin_amdgcn_rcpf(delta);   // fast-path reciprocal
    const int   dbits  = __float_as_int(delta);

#pragma unroll
    for (int i = 0; i < 6; ++i) {
        float r[4] = {v[i].x, v[i].y, v[i].z, v[i].w};
        float o[4];
#pragma unroll
        for (int j = 0; j < 4; ++j) {
            const float rf = fmaxf(r[j] * rdelta, 1e-8f);
            const unsigned int bits = __float_as_uint(rf);
            const unsigned int diff = 0x3FB504F3u - bits;   // >0 for rf in [1e-8, ~1.4)
            int kq = (int)(diff >> 23);                     // exact rint(-log2(rf))
            const unsigned int d2 = (diff + 2048u) & 0x7FFFFFu;
            if (d2 < 4096u) {
                // near a half-integer cliff: replicate ref chain exactly
                const float ratio = fmaxf(r[j] / delta, 1e-8f);  // IEEE f32 div
                const float tt = (float)log((double)ratio);
                const float v2 = tt / 0x1.62e43p-1f;             // fl32(ln 2)
                kq = (int)rintf(-v2);
            }
            // out = delta * 2^-kq exactly, via exponent decrement (kq in [0,27])
            o[j] = __int_as_float(dbits - (kq << 23));
        }
        vf4 ov = {o[0], o[1], o[2], o[3]};
        // NT store: don't allocate out in L3; preserve x residency across replays
        __builtin_nontemporal_store(ov, reinterpret_cast<vf4*>(out + base + (size_t)(2 * i) * HSTRIDE));
    }
}

extern "C" void kernel_launch(void* const* d_in, const int* in_sizes, int n_in,
                              void* d_out, int out_size, void* d_ws, size_t ws_size,
                              hipStream_t stream) {
    const float* x = (const float*)d_in[0];
    float* out = (float*)d_out;
    dim3 grid((BB * TT) / 8);   // 4096 blocks, 4 wave-pairs each (8 groups)
    dim3 block(256);
    log2q_kernel<<<grid, block, 0, stream>>>(x, out);
}